// Round 2
// baseline (1166.096 us; speedup 1.0000x reference)
//
#include <hip/hip_runtime.h>
#include <hip/hip_bf16.h>

// R2: all intermediates fp32; GEMMs use split-bf16 (hi+lo, 3 MFMAs) so h matches
// the fp32 reference to ~1e-5 rel — required because top-2 MoE routing is
// discontinuous and must match the reference's expert selection exactly.
// Vocab GEMM (67 of 98 GFLOP) stays single-bf16: output tolerance is 3% of max.

#define BT   2048
#define TSEQ 1024
#define CDIM 512
#define NKVD 128
#define NEXP 8
#define NVOC 32000

using bf16 = __hip_bfloat16;
typedef __attribute__((ext_vector_type(8))) short short8;
typedef __attribute__((ext_vector_type(4))) float floatx4;

// ---------------------------------------------------------------- helpers

// truncation split: v = hi + lo + r, |r| <= 2^-17 |v|
__device__ inline void split8(const float* __restrict__ src, short8& hi, short8& lo) {
    float4 f0 = *reinterpret_cast<const float4*>(src);
    float4 f1 = *reinterpret_cast<const float4*>(src + 4);
    float v[8] = {f0.x, f0.y, f0.z, f0.w, f1.x, f1.y, f1.z, f1.w};
    #pragma unroll
    for (int j = 0; j < 8; ++j) {
        unsigned u = __builtin_bit_cast(unsigned, v[j]);
        hi[j] = (short)(u >> 16);
        float hf = __builtin_bit_cast(float, u & 0xffff0000u);
        float r = v[j] - hf;
        lo[j] = (short)(__builtin_bit_cast(unsigned, r) >> 16);
    }
}

// RTN f32 -> bf16 x8 (for the hi-only vocab GEMM)
__device__ inline short8 cvt8(const float* __restrict__ src) {
    float4 f0 = *reinterpret_cast<const float4*>(src);
    float4 f1 = *reinterpret_cast<const float4*>(src + 4);
    float v[8] = {f0.x, f0.y, f0.z, f0.w, f1.x, f1.y, f1.z, f1.w};
    short8 h;
    #pragma unroll
    for (int j = 0; j < 8; ++j) {
        unsigned u = __builtin_bit_cast(unsigned, v[j]);
        u = u + 0x7fffu + ((u >> 16) & 1u);
        h[j] = (short)(u >> 16);
    }
    return h;
}

__global__ void embed_k(const int* __restrict__ ids, const float* __restrict__ tok,
                        const float* __restrict__ pos, float* __restrict__ h) {
    int n = blockIdx.x, t = threadIdx.x;
    int id = ids[n];
    int p = n & (TSEQ - 1);
    for (int c = t; c < CDIM; c += 256)
        h[(long)n * CDIM + c] = tok[(long)id * CDIM + c] + pos[(long)p * CDIM + c];
}

__global__ void rms_k(const float* __restrict__ x, const float* __restrict__ w,
                      float* __restrict__ out) {
    int n = blockIdx.x, t = threadIdx.x;
    const float* xr = x + (long)n * CDIM;
    float v0 = xr[t], v1 = xr[t + 256];
    float ss = v0 * v0 + v1 * v1;
    #pragma unroll
    for (int o = 32; o > 0; o >>= 1) ss += __shfl_down(ss, o);
    __shared__ float red[4];
    if ((t & 63) == 0) red[t >> 6] = ss;
    __syncthreads();
    float tot = red[0] + red[1] + red[2] + red[3];
    float rstd = 1.0f / sqrtf(tot * (1.0f / CDIM) + 1e-6f);
    out[(long)n * CDIM + t]       = v0 * rstd * w[t];
    out[(long)n * CDIM + t + 256] = v1 * rstd * w[t + 256];
}

// ---------------------------------------------------------------- GEMM
// D[M,N] (+)= A[M,K] * B[N,K]^T, fp32 in/out, split-bf16 MFMA inside.
template<int BM, int BN, bool SPLIT, bool ACCUM>
__global__ __launch_bounds__(256, 2)
void gemm_f32(const float* __restrict__ A, const float* __restrict__ B,
              float* __restrict__ D, int M, int N, int Kd,
              int lda, int ldb, int ldd,
              long aBatch, long bBatch, int dDiv, long dOuter, long dInner)
{
    constexpr int BK = 64;
    constexpr int WM = BM / 2, WN = BN / 2;
    constexpr int TM = WM / 16, TN = WN / 16;
    constexpr int LDP = BK + 8;
    __shared__ bf16 AsH[BM][LDP];
    __shared__ bf16 BsH[BN][LDP];
    __shared__ bf16 AsL[SPLIT ? BM : 1][SPLIT ? LDP : 1];
    __shared__ bf16 BsL[SPLIT ? BN : 1][SPLIT ? LDP : 1];

    int z = blockIdx.z;
    const float* Ap = A + (long)z * aBatch;
    const float* Bp = B + (long)z * bBatch;
    long dOff = (long)(z / dDiv) * dOuter + (long)(z % dDiv) * dInner;
    int bm = blockIdx.y * BM;
    int bn = blockIdx.x * BN;
    int tid = threadIdx.x;
    int wave = tid >> 6, lane = tid & 63;
    int wm = (wave >> 1) * WM, wn = (wave & 1) * WN;
    int lrow = lane & 15, quad = lane >> 4;

    floatx4 acc[TM][TN];
    #pragma unroll
    for (int i = 0; i < TM; ++i)
        #pragma unroll
        for (int j = 0; j < TN; ++j)
            acc[i][j] = (floatx4){0.f, 0.f, 0.f, 0.f};

    constexpr int ACH = BM * BK / (8 * 256);
    constexpr int BCH = BN * BK / (8 * 256);

    for (int k0 = 0; k0 < Kd; k0 += BK) {
        #pragma unroll
        for (int i = 0; i < ACH; ++i) {
            int c = tid + i * 256;
            int r = c >> 3, c8 = (c & 7) << 3;
            const float* src = Ap + (long)(bm + r) * lda + k0 + c8;
            if constexpr (SPLIT) {
                short8 hi, lo;
                split8(src, hi, lo);
                *reinterpret_cast<short8*>(&AsH[r][c8]) = hi;
                *reinterpret_cast<short8*>(&AsL[r][c8]) = lo;
            } else {
                *reinterpret_cast<short8*>(&AsH[r][c8]) = cvt8(src);
            }
        }
        #pragma unroll
        for (int i = 0; i < BCH; ++i) {
            int c = tid + i * 256;
            int r = c >> 3, c8 = (c & 7) << 3;
            const float* src = Bp + (long)(bn + r) * ldb + k0 + c8;
            if constexpr (SPLIT) {
                short8 hi, lo;
                split8(src, hi, lo);
                *reinterpret_cast<short8*>(&BsH[r][c8]) = hi;
                *reinterpret_cast<short8*>(&BsL[r][c8]) = lo;
            } else {
                *reinterpret_cast<short8*>(&BsH[r][c8]) = cvt8(src);
            }
        }
        __syncthreads();
        #pragma unroll
        for (int kc = 0; kc < BK / 32; ++kc) {
            short8 ah[TM], bh[TN], al[TM], bl[TN];
            #pragma unroll
            for (int i = 0; i < TM; ++i) {
                ah[i] = *reinterpret_cast<const short8*>(&AsH[wm + i * 16 + lrow][kc * 32 + quad * 8]);
                if constexpr (SPLIT)
                    al[i] = *reinterpret_cast<const short8*>(&AsL[wm + i * 16 + lrow][kc * 32 + quad * 8]);
            }
            #pragma unroll
            for (int j = 0; j < TN; ++j) {
                bh[j] = *reinterpret_cast<const short8*>(&BsH[wn + j * 16 + lrow][kc * 32 + quad * 8]);
                if constexpr (SPLIT)
                    bl[j] = *reinterpret_cast<const short8*>(&BsL[wn + j * 16 + lrow][kc * 32 + quad * 8]);
            }
            #pragma unroll
            for (int i = 0; i < TM; ++i)
                #pragma unroll
                for (int j = 0; j < TN; ++j) {
                    acc[i][j] = __builtin_amdgcn_mfma_f32_16x16x32_bf16(ah[i], bh[j], acc[i][j], 0, 0, 0);
                    if constexpr (SPLIT) {
                        acc[i][j] = __builtin_amdgcn_mfma_f32_16x16x32_bf16(ah[i], bl[j], acc[i][j], 0, 0, 0);
                        acc[i][j] = __builtin_amdgcn_mfma_f32_16x16x32_bf16(al[i], bh[j], acc[i][j], 0, 0, 0);
                    }
                }
        }
        __syncthreads();
    }

    // C/D: col = lane&15, row = quad*4 + reg  [m89-verified]
    #pragma unroll
    for (int i = 0; i < TM; ++i)
        #pragma unroll
        for (int j = 0; j < TN; ++j) {
            int row = bm + wm + i * 16 + quad * 4;
            int col = bn + wn + j * 16 + lrow;
            #pragma unroll
            for (int r = 0; r < 4; ++r) {
                long idx = dOff + (long)(row + r) * ldd + col;
                if constexpr (ACCUM) D[idx] += acc[i][j][r];
                else                 D[idx]  = acc[i][j][r];
            }
        }
}

// ---------------------------------------------------------------- attention

__global__ void pack_k(const float* __restrict__ Qb, const float* __restrict__ Kb,
                       const float* __restrict__ Vb, float* __restrict__ Qp,
                       float* __restrict__ Kp, float* __restrict__ Vt) {
    long id = (long)blockIdx.x * 256 + threadIdx.x;  // 16*1024*64
    int d = id & 63;
    int t = (id >> 6) & (TSEQ - 1);
    int z = id >> 16;
    int b = z >> 3, hh = z & 7, kvh = hh >> 2;
    long src = (long)(b * TSEQ + t);
    Qp[id] = Qb[src * CDIM + hh * 64 + d];
    Kp[id] = Kb[src * NKVD + kvh * 64 + d];
    Vt[((long)z * 64 + d) * TSEQ + t] = Vb[src * NKVD + kvh * 64 + d];
}

// causal scaled softmax, in place: S[z][q][:] -> probabilities (0 above diag)
__global__ void softmax_k(float* __restrict__ S) {
    int q = blockIdx.x, z = blockIdx.y, t = threadIdx.x;
    float* srow = S + ((long)z * TSEQ + q) * TSEQ;
    int len = q + 1;
    const float sc = 0.125f;
    float mx = -3.0e38f;
    for (int k = t; k < len; k += 256) mx = fmaxf(mx, srow[k]);
    #pragma unroll
    for (int o = 32; o > 0; o >>= 1) mx = fmaxf(mx, __shfl_down(mx, o));
    __shared__ float red[8];
    if ((t & 63) == 0) red[t >> 6] = mx;
    __syncthreads();
    mx = fmaxf(fmaxf(red[0], red[1]), fmaxf(red[2], red[3]));
    float sum = 0.f;
    for (int k = t; k < len; k += 256) sum += __expf((srow[k] - mx) * sc);
    #pragma unroll
    for (int o = 32; o > 0; o >>= 1) sum += __shfl_down(sum, o);
    if ((t & 63) == 0) red[4 + (t >> 6)] = sum;
    __syncthreads();
    float inv = 1.0f / (red[4] + red[5] + red[6] + red[7]);
    for (int k = t; k < TSEQ; k += 256) {
        float p = (k < len) ? __expf((srow[k] - mx) * sc) * inv : 0.0f;
        srow[k] = p;
    }
}

// ---------------------------------------------------------------- MoE

__global__ void route_k(const float* __restrict__ h, const float* __restrict__ w,
                        const float* __restrict__ gw, float* __restrict__ comb) {
    int n = blockIdx.x, t = threadIdx.x;
    const float* xr = h + (long)n * CDIM;
    float v0 = xr[t], v1 = xr[t + 256];
    float ss = v0 * v0 + v1 * v1;
    #pragma unroll
    for (int o = 32; o > 0; o >>= 1) ss += __shfl_down(ss, o);
    __shared__ float rr[4];
    __shared__ float ac[4][8];
    if ((t & 63) == 0) rr[t >> 6] = ss;
    __syncthreads();
    float tot = rr[0] + rr[1] + rr[2] + rr[3];
    float rstd = 1.0f / sqrtf(tot * (1.0f / CDIM) + 1e-6f);
    float x0 = v0 * rstd * w[t], x1 = v1 * rstd * w[t + 256];
    float pe[NEXP];
    #pragma unroll
    for (int e = 0; e < NEXP; ++e)
        pe[e] = x0 * gw[e * CDIM + t] + x1 * gw[e * CDIM + t + 256];
    #pragma unroll
    for (int e = 0; e < NEXP; ++e)
        #pragma unroll
        for (int o = 32; o > 0; o >>= 1) pe[e] += __shfl_down(pe[e], o);
    if ((t & 63) == 0)
        #pragma unroll
        for (int e = 0; e < NEXP; ++e) ac[t >> 6][e] = pe[e];
    __syncthreads();
    if (t == 0) {
        float lg[NEXP];
        #pragma unroll
        for (int e = 0; e < NEXP; ++e) lg[e] = ac[0][e] + ac[1][e] + ac[2][e] + ac[3][e];
        int i1 = 0; float l1 = lg[0];
        #pragma unroll
        for (int e = 1; e < NEXP; ++e) if (lg[e] > l1) { l1 = lg[e]; i1 = e; }
        int i2 = -1; float l2 = -3.0e38f;
        #pragma unroll
        for (int e = 0; e < NEXP; ++e) if (e != i1 && lg[e] > l2) { l2 = lg[e]; i2 = e; }
        float e2 = __expf(l2 - l1);
        float dnm = 1.0f + e2;
        float* cr = comb + (long)n * NEXP;
        #pragma unroll
        for (int e = 0; e < NEXP; ++e) cr[e] = 0.f;
        cr[i1] = 1.0f / dnm;
        cr[i2] = e2 / dnm;
    }
}

__global__ void combine_k(float* __restrict__ h, const float* __restrict__ allout,
                          const float* __restrict__ comb) {
    int n = blockIdx.x, t = threadIdx.x;
    __shared__ float cw[NEXP];
    if (t < NEXP) cw[t] = comb[(long)n * NEXP + t];
    __syncthreads();
    for (int c = t; c < CDIM; c += 256) {
        float a = h[(long)n * CDIM + c];
        #pragma unroll
        for (int e = 0; e < NEXP; ++e) {
            float wv = cw[e];
            if (wv != 0.0f) a += wv * allout[((long)e * BT + n) * CDIM + c];
        }
        h[(long)n * CDIM + c] = a;
    }
}

// ---------------------------------------------------------------- launch

extern "C" void kernel_launch(void* const* d_in, const int* in_sizes, int n_in,
                              void* d_out, int out_size, void* d_ws, size_t ws_size,
                              hipStream_t stream) {
    const int*   ids  = (const int*)d_in[0];
    const float* tok  = (const float*)d_in[1];
    const float* pos  = (const float*)d_in[2];
    const float* anw  = (const float*)d_in[3];
    const float* qw   = (const float*)d_in[4];
    const float* kw   = (const float*)d_in[5];
    const float* vw   = (const float*)d_in[6];
    const float* ow   = (const float*)d_in[7];
    const float* fnw  = (const float*)d_in[8];
    const float* gw   = (const float*)d_in[9];
    const float* ew   = (const float*)d_in[10];
    const float* finw = (const float*)d_in[11];
    const float* outw = (const float*)d_in[12];
    float* out = (float*)d_out;

    char* wsp = (char*)d_ws;
    auto alloc = [&](size_t bytes) -> char* {
        char* p = wsp;
        wsp += (bytes + 255) & ~(size_t)255;
        return p;
    };
    float* H    = (float*)alloc((size_t)BT * CDIM * 4);
    float* XN   = (float*)alloc((size_t)BT * CDIM * 4);
    float* QB   = (float*)alloc((size_t)BT * CDIM * 4);
    float* KB   = (float*)alloc((size_t)BT * NKVD * 4);
    float* VB   = (float*)alloc((size_t)BT * NKVD * 4);
    float* QP   = (float*)alloc((size_t)16 * TSEQ * 64 * 4);
    float* KP   = (float*)alloc((size_t)16 * TSEQ * 64 * 4);
    float* VT   = (float*)alloc((size_t)16 * TSEQ * 64 * 4);
    float* AOB  = (float*)alloc((size_t)BT * CDIM * 4);
    float* SS   = (float*)alloc((size_t)16 * TSEQ * TSEQ * 4);  // scores/P; reused as allout
    float* COMB = (float*)alloc((size_t)BT * NEXP * 4);

    embed_k<<<dim3(BT), dim3(256), 0, stream>>>(ids, tok, pos, H);

    for (int l = 0; l < 2; ++l) {
        const float* qwl = qw + (long)l * CDIM * CDIM;
        const float* kwl = kw + (long)l * NKVD * CDIM;
        const float* vwl = vw + (long)l * NKVD * CDIM;
        const float* owl = ow + (long)l * CDIM * CDIM;
        const float* ewl = ew + (long)l * NEXP * CDIM * CDIM;

        rms_k<<<dim3(BT), dim3(256), 0, stream>>>(H, anw + l * CDIM, XN);
        gemm_f32<128,128,true,false><<<dim3(4,16,1), dim3(256), 0, stream>>>(
            XN, qwl, QB, BT, CDIM, CDIM, CDIM, CDIM, CDIM, 0, 0, 1, 0, 0);
        gemm_f32<128,128,true,false><<<dim3(1,16,1), dim3(256), 0, stream>>>(
            XN, kwl, KB, BT, NKVD, CDIM, CDIM, CDIM, NKVD, 0, 0, 1, 0, 0);
        gemm_f32<128,128,true,false><<<dim3(1,16,1), dim3(256), 0, stream>>>(
            XN, vwl, VB, BT, NKVD, CDIM, CDIM, CDIM, NKVD, 0, 0, 1, 0, 0);
        pack_k<<<dim3(4096), dim3(256), 0, stream>>>(QB, KB, VB, QP, KP, VT);
        // S[z] = Qp[z] @ Kp[z]^T
        gemm_f32<128,128,true,false><<<dim3(8,8,16), dim3(256), 0, stream>>>(
            QP, KP, SS, TSEQ, TSEQ, 64, 64, 64, TSEQ,
            (long)TSEQ * 64, (long)TSEQ * 64, 1, (long)TSEQ * TSEQ, 0);
        softmax_k<<<dim3(TSEQ, 16), dim3(256), 0, stream>>>(SS);
        // AOB[b*T+t][h*64+d] = P[z] @ Vt[z]^T
        gemm_f32<128,64,true,false><<<dim3(1,8,16), dim3(256), 0, stream>>>(
            SS, VT, AOB, TSEQ, 64, TSEQ, TSEQ, TSEQ, CDIM,
            (long)TSEQ * TSEQ, (long)64 * TSEQ, 8, (long)TSEQ * CDIM, 64);
        // H += AOB @ o_w^T
        gemm_f32<128,128,true,true><<<dim3(4,16,1), dim3(256), 0, stream>>>(
            AOB, owl, H, BT, CDIM, CDIM, CDIM, CDIM, CDIM, 0, 0, 1, 0, 0);
        // MoE
        route_k<<<dim3(BT), dim3(256), 0, stream>>>(H, fnw + l * CDIM, gw + (long)l * NEXP * CDIM, COMB);
        rms_k<<<dim3(BT), dim3(256), 0, stream>>>(H, fnw + l * CDIM, XN);
        gemm_f32<128,128,true,false><<<dim3(4,16,8), dim3(256), 0, stream>>>(
            XN, ewl, SS, BT, CDIM, CDIM, CDIM, CDIM, CDIM,
            0, (long)CDIM * CDIM, 1, (long)BT * CDIM, 0);
        combine_k<<<dim3(BT), dim3(256), 0, stream>>>(H, SS, COMB);
    }

    rms_k<<<dim3(BT), dim3(256), 0, stream>>>(H, finw, XN);
    gemm_f32<128,128,false,false><<<dim3(250,16,1), dim3(256), 0, stream>>>(
        XN, outw, out, BT, NVOC, CDIM, CDIM, CDIM, NVOC, 0, 0, 1, 0, 0);
}